// Round 12
// baseline (445.763 us; speedup 1.0000x reference)
//
#include <hip/hip_runtime.h>
#include <hip/hip_fp16.h>

#define DIAGNUM 50000
#define MEDNUM  20000
#define PRONUM  40000
#define FEATDIM 128
#define N1 (DIAGNUM + MEDNUM)   // 70000
#define N2 (PRONUM + MEDNUM)    // 60000
#define NNZ1 1120000
#define NNZ2 960000
#define NTOT (2 * N1 + 2 * N2)            // 260000 concatenated rows
#define NNZTOT (2 * NNZ1 + 2 * NNZ2)      // 4160000 concatenated edges
#define NBUCK ((NTOT + 255) >> 8)         // 1016 buckets of 256 rows
#define L1_THREADS 512
#define L1_CHUNK 8192
#define L1_ITERS (L1_CHUNK / L1_THREADS)  // 16
#define L1_BLOCKS ((NNZTOT + L1_CHUNK - 1) / L1_CHUNK)   // 508

typedef unsigned short ushort_t;
typedef float f32x4 __attribute__((ext_vector_type(4)));

// concatenated row index for edge i
__device__ __forceinline__ int edge_idx(int i, const int* __restrict__ a1r,
                                        const int* __restrict__ a2r) {
    if (i < 2 * NNZ1) {
        return ((i < NNZ1) ? 0 : N1) + __builtin_nontemporal_load(a1r + i);
    } else {
        int j = i - 2 * NNZ1;
        return 2 * N1 + ((j < NNZ2) ? 0 : N2) + __builtin_nontemporal_load(a2r + j);
    }
}

// ---------------- bucket count ----------------
__global__ __launch_bounds__(256) void count_buckets_kernel(
        const int* __restrict__ a1r, const int* __restrict__ a2r,
        int* __restrict__ bucketCnt) {
    __shared__ int lh[NBUCK];
    for (int b = threadIdx.x; b < NBUCK; b += 256) lh[b] = 0;
    __syncthreads();
    int stride = gridDim.x * 256;
    for (int i = blockIdx.x * 256 + threadIdx.x; i < NNZTOT; i += stride)
        atomicAdd(&lh[edge_idx(i, a1r, a2r) >> 8], 1);
    __syncthreads();
    for (int b = threadIdx.x; b < NBUCK; b += 256) {
        int h = lh[b];
        if (h) atomicAdd(&bucketCnt[b], h);
    }
}

// ---------------- exclusive scan of bucket counts (single block) ----------------
__global__ __launch_bounds__(256) void scan_buckets_kernel(
        const int* __restrict__ bucketCnt, int* __restrict__ bucketOff,
        int* __restrict__ cursor) {
    __shared__ int s[256];
    int t = threadIdx.x;
    int vals[4];
    int sum = 0;
#pragma unroll
    for (int k = 0; k < 4; k++) {
        int b = t * 4 + k;
        vals[k] = (b < NBUCK) ? bucketCnt[b] : 0;
        sum += vals[k];
    }
    s[t] = sum;
    __syncthreads();
    for (int off = 1; off < 256; off <<= 1) {
        int y = (t >= off) ? s[t - off] : 0;
        __syncthreads();
        s[t] += y;
        __syncthreads();
    }
    int run = s[t] - sum;
#pragma unroll
    for (int k = 0; k < 4; k++) {
        int b = t * 4 + k;
        if (b < NBUCK) {
            bucketOff[b] = run;
            cursor[b] = run;
            run += vals[k];
        }
    }
    if (t == 255) bucketOff[NBUCK] = run;   // == NNZTOT
}

// ---------------- level-1 scatter into coarse buckets ----------------
// 512 threads x 8192-edge chunks; row indices cached in registers across
// sweeps. Record split: cols word (row_local<<17)|col (4 B) + fp16 val (2 B).
__global__ __launch_bounds__(L1_THREADS) void lvl1_scatter_kernel(
        const int* __restrict__ a1r, const int* __restrict__ a1c,
        const float* __restrict__ a1v,
        const int* __restrict__ a2r, const int* __restrict__ a2c,
        const float* __restrict__ a2v,
        int* __restrict__ cursor,
        int* __restrict__ l1cols, ushort_t* __restrict__ l1vals) {
    __shared__ int lh[NBUCK];
    for (int b = threadIdx.x; b < NBUCK; b += L1_THREADS) lh[b] = 0;
    __syncthreads();
    int base = blockIdx.x * L1_CHUNK;
    int end  = min(base + L1_CHUNK, NNZTOT);
    int idxv[L1_ITERS];
    // sweep 1: block-local bucket histogram (cache idx)
    {
        int it = 0;
        for (int i = base + threadIdx.x; i < end; i += L1_THREADS, it++) {
            int idx = edge_idx(i, a1r, a2r);
            idxv[it] = idx;
            atomicAdd(&lh[idx >> 8], 1);
        }
    }
    __syncthreads();
    // reserve spans: lh[b] becomes this block's rolling global cursor
    for (int b = threadIdx.x; b < NBUCK; b += L1_THREADS) {
        int h = lh[b];
        lh[b] = h ? atomicAdd(&cursor[b], h) : 0;
    }
    __syncthreads();
    // sweep 2: write records (col/val only; idx from registers)
    {
        int it = 0;
        for (int i = base + threadIdx.x; i < end; i += L1_THREADS, it++) {
            int col;
            float val;
            if (i < 2 * NNZ1) {
                col = __builtin_nontemporal_load(a1c + i);
                val = __builtin_nontemporal_load(a1v + i);
            } else {
                int j = i - 2 * NNZ1;
                col = __builtin_nontemporal_load(a2c + j);
                val = __builtin_nontemporal_load(a2v + j);
            }
            int idx = idxv[it];
            int pos = atomicAdd(&lh[idx >> 8], 1);
            l1cols[pos] = ((idx & 255) << 17) | col;
            l1vals[pos] = __half_as_ushort(__float2half(val));
        }
    }
}

// ---------------- level-2 sort within bucket (one block per bucket) ----------------
// Block exclusively owns its ~16 KB destination range -> clean full-line writes.
// Final record: 4 B = (fp16(val) << 17) | col  (val in [0,1): sign=0, 15 bits).
// Also writes rpe[idx+1] = row end offsets.
__global__ __launch_bounds__(256) void lvl2_sort_kernel(
        const int* __restrict__ l1cols, const ushort_t* __restrict__ l1vals,
        const int* __restrict__ bucketOff,
        int* __restrict__ binned, int* __restrict__ rpe) {
    __shared__ int cnt[256];
    __shared__ int sc[256];
    int b = blockIdx.x;
    int t = threadIdx.x;
    int s0 = bucketOff[b];
    int e0 = bucketOff[b + 1];
    cnt[t] = 0;
    __syncthreads();
    for (int k = s0 + t; k < e0; k += 256)
        atomicAdd(&cnt[__builtin_nontemporal_load(l1cols + k) >> 17], 1);
    __syncthreads();
    int v = cnt[t];
    sc[t] = v;
    __syncthreads();
    for (int off = 1; off < 256; off <<= 1) {
        int y = (t >= off) ? sc[t - off] : 0;
        __syncthreads();
        sc[t] += y;
        __syncthreads();
    }
    int incl = sc[t];
    int excl = incl - v;
    int idx = (b << 8) + t;
    if (idx < NTOT) rpe[idx + 1] = s0 + incl;
    cnt[t] = excl;   // repurpose as local cursor
    __syncthreads();
    for (int k = s0 + t; k < e0; k += 256) {
        int c  = __builtin_nontemporal_load(l1cols + k);
        unsigned hv = __builtin_nontemporal_load(l1vals + k);
        int rl  = c >> 17;
        int col = c & 0x1FFFF;
        int pos = atomicAdd(&cnt[rl], 1);
        binned[s0 + pos] = (int)((hv << 17) | (unsigned)col);
    }
}

// ---------------- fp16 embedding conversion (unified per-graph layouts) ----------------
// emb1 = [dE; mE] (N1 x 128), emb2 = [pE; mE] (N2 x 128); med rows duplicated.
#define TOT8 ((DIAGNUM + MEDNUM + PRONUM) * (FEATDIM / 8))   // 1,760,000

__device__ __forceinline__ ushort_t f2h(float x) {
    return __half_as_ushort(__float2half(x));
}

__global__ __launch_bounds__(256) void convert_emb_kernel(
        const float* __restrict__ dE, const float* __restrict__ mE,
        const float* __restrict__ pE,
        ushort_t* __restrict__ emb1, ushort_t* __restrict__ emb2) {
    int t8 = blockIdx.x * 256 + threadIdx.x;
    if (t8 >= TOT8) return;
    long flat = (long)t8 * 8;
    const float* src;
    ushort_t* dst;
    ushort_t* dst2 = nullptr;
    if (flat < (long)DIAGNUM * FEATDIM) {
        src = dE + flat;
        dst = emb1 + flat;
    } else if (flat < (long)(DIAGNUM + MEDNUM) * FEATDIM) {
        long o = flat - (long)DIAGNUM * FEATDIM;
        src = mE + o;
        dst  = emb1 + (long)DIAGNUM * FEATDIM + o;
        dst2 = emb2 + (long)PRONUM * FEATDIM + o;
    } else {
        long o = flat - (long)(DIAGNUM + MEDNUM) * FEATDIM;
        src = pE + o;
        dst = emb2 + o;
    }
    float4 a = *reinterpret_cast<const float4*>(src);
    float4 b = *reinterpret_cast<const float4*>(src + 4);
    int4 w;
    w.x = (int)((unsigned)f2h(a.x) | ((unsigned)f2h(a.y) << 16));
    w.y = (int)((unsigned)f2h(a.z) | ((unsigned)f2h(a.w) << 16));
    w.z = (int)((unsigned)f2h(b.x) | ((unsigned)f2h(b.y) << 16));
    w.w = (int)((unsigned)f2h(b.z) | ((unsigned)f2h(b.w) << 16));
    *reinterpret_cast<int4*>(dst) = w;
    if (dst2) *reinterpret_cast<int4*>(dst2) = w;
}

// ---------------- fused GCN row kernel (quarter-wave fp16 gather, 2x unroll) ----------------
// 16 lanes x 16 B (8 fp16) per edge, 8 edges in flight per wave.
// Edge records streamed with nontemporal loads (protect L2 for embeddings).

__device__ __forceinline__ void fma8(float acc[8], float v, int4 h) {
    union U { int4 i; __half2 h2[4]; } u;
    u.i = h;
#pragma unroll
    for (int j = 0; j < 4; j++) {
        float2 f = __half22float2(u.h2[j]);
        acc[2 * j]     = fmaf(v, f.x, acc[2 * j]);
        acc[2 * j + 1] = fmaf(v, f.y, acc[2 * j + 1]);
    }
}

__device__ __forceinline__ float rec_val(unsigned rec) {
    return __half2float(__ushort_as_half((unsigned short)(rec >> 17)));
}

__device__ __forceinline__ void gather8(int s, int e,
                                        const int* __restrict__ binned,
                                        int q, int sub16,
                                        const ushort_t* __restrict__ emb,
                                        float acc[8]) {
    int k = s + q;
    for (; k + 4 < e; k += 8) {
        unsigned r0 = (unsigned)__builtin_nontemporal_load(binned + k);
        unsigned r1 = (unsigned)__builtin_nontemporal_load(binned + k + 4);
        const int4* b0 = reinterpret_cast<const int4*>(emb + ((size_t)(r0 & 0x1FFFFu) << 7));
        const int4* b1 = reinterpret_cast<const int4*>(emb + ((size_t)(r1 & 0x1FFFFu) << 7));
        int4 h0 = b0[sub16];
        int4 h1 = b1[sub16];
        fma8(acc, rec_val(r0), h0);
        fma8(acc, rec_val(r1), h1);
    }
    for (; k < e; k += 4) {
        unsigned r0 = (unsigned)__builtin_nontemporal_load(binned + k);
        const int4* b0 = reinterpret_cast<const int4*>(emb + ((size_t)(r0 & 0x1FFFFu) << 7));
        int4 h0 = b0[sub16];
        fma8(acc, rec_val(r0), h0);
    }
}

__device__ __forceinline__ void nt_store4(float* p, float a, float b,
                                          float c, float d) {
    f32x4 v = {a, b, c, d};
    __builtin_nontemporal_store(v, reinterpret_cast<f32x4*>(p));
}

// ONE launch for both graphs: w < N2 -> graph2, else graph1 (row w-N2).
// Med rows: atomicAdd(scale*res) into zero-initialized out_m
// (scale = 1-t for graph2, t for graph1) -> no ordering dependency.
__global__ __launch_bounds__(256) void fused_gcn_kernel(
        const int* __restrict__ rpe,
        const int* __restrict__ binned,
        const ushort_t* __restrict__ emb1, const ushort_t* __restrict__ emb2,
        const float* __restrict__ inter,
        float* __restrict__ out_d, float* __restrict__ out_p,
        float* __restrict__ out_m) {
    int gtid = blockIdx.x * blockDim.x + threadIdx.x;
    int w     = gtid >> 6;
    int lane  = gtid & 63;
    int q     = lane >> 4;
    int sub16 = lane & 15;
    if (w >= N1 + N2) return;

    const ushort_t* emb;
    const int *rpA, *rpB;
    int r, graph;
    if (w < N2) {   // graph 2
        graph = 0; r = w; emb = emb2;
        rpA = rpe + 2 * N1 + r;
        rpB = rpe + 2 * N1 + N2 + r;
    } else {        // graph 1
        graph = 1; r = w - N2; emb = emb1;
        rpA = rpe + r;
        rpB = rpe + N1 + r;
    }

    float aA[8] = {0, 0, 0, 0, 0, 0, 0, 0};
    float aB[8] = {0, 0, 0, 0, 0, 0, 0, 0};
    gather8(rpA[0], rpA[1], binned, q, sub16, emb, aA);
    gather8(rpB[0], rpB[1], binned, q, sub16, emb, aB);

    // reduce the 4 quarters
#pragma unroll
    for (int j = 0; j < 8; j++) {
        aA[j] += __shfl_xor(aA[j], 16);
        aA[j] += __shfl_xor(aA[j], 32);
        aB[j] += __shfl_xor(aB[j], 16);
        aB[j] += __shfl_xor(aB[j], 32);
    }

    if (lane >= 16) return;

    float res[8];
#pragma unroll
    for (int j = 0; j < 8; j++)
        res[j] = 2.f * (fmaxf(aA[j], 0.f) + fmaxf(aB[j], 0.f));

    if (graph) {
        if (r < DIAGNUM) {
            float* dst = out_d + (size_t)r * FEATDIM + sub16 * 8;
            nt_store4(dst,     res[0], res[1], res[2], res[3]);
            nt_store4(dst + 4, res[4], res[5], res[6], res[7]);
        } else {
            float t = *inter;
            float* dst = out_m + (size_t)(r - DIAGNUM) * FEATDIM + sub16 * 8;
#pragma unroll
            for (int j = 0; j < 8; j++) atomicAdd(dst + j, t * res[j]);
        }
    } else {
        if (r < PRONUM) {
            float* dst = out_p + (size_t)r * FEATDIM + sub16 * 8;
            nt_store4(dst,     res[0], res[1], res[2], res[3]);
            nt_store4(dst + 4, res[4], res[5], res[6], res[7]);
        } else {
            float sc = 1.0f - *inter;
            float* dst = out_m + (size_t)(r - PRONUM) * FEATDIM + sub16 * 8;
#pragma unroll
            for (int j = 0; j < 8; j++) atomicAdd(dst + j, sc * res[j]);
        }
    }
}

// ---------------- host orchestration ----------------

extern "C" void kernel_launch(void* const* d_in, const int* in_sizes, int n_in,
                              void* d_out, int out_size, void* d_ws, size_t ws_size,
                              hipStream_t stream) {
    const int*   a1r = (const int*)d_in[0];
    const int*   a1c = (const int*)d_in[1];
    const float* a1v = (const float*)d_in[2];
    const int*   a2r = (const int*)d_in[3];
    const int*   a2c = (const int*)d_in[4];
    const float* a2v = (const float*)d_in[5];
    const float* dE  = (const float*)d_in[6];
    const float* mE  = (const float*)d_in[7];
    const float* pE  = (const float*)d_in[8];
    const float* inter = (const float*)d_in[9];

    float* out   = (float*)d_out;
    float* out_m = out;                               // 20000*128
    float* out_d = out + (size_t)MEDNUM * FEATDIM;    // 50000*128
    float* out_p = out_d + (size_t)DIAGNUM * FEATDIM; // 40000*128

    // ws layout (~51 MB). regionB is time-shared: lvl1 split records (sort
    // phase: cols 16.64 MB + vals 8.32 MB), then fp16 unified embeddings
    // (emb1 17.92 + emb2 15.36 = 33.28 MB) — lvl1 dead after lvl2_sort.
    char* ws = (char*)d_ws;
    int* binned = (int*)ws;          ws += (size_t)NNZTOT * 4;          // 16.64 MB
    char* regionB = ws;              ws += (size_t)NNZTOT * 8;          // 33.28 MB
    int*      l1cols = (int*)regionB;
    ushort_t* l1vals = (ushort_t*)(regionB + (size_t)NNZTOT * 4);
    ushort_t* emb1 = (ushort_t*)regionB;                    // N1*128 fp16
    ushort_t* emb2 = emb1 + (size_t)N1 * FEATDIM;           // N2*128 fp16
    int* rpe       = (int*)ws;       ws += (((size_t)(NTOT + 1) * 4 + 15) & ~15ull);
    int* bucketCnt = (int*)ws;       ws += (size_t)NBUCK * 4;
    int* bucketOff = (int*)ws;       ws += (size_t)(NBUCK + 1) * 4;
    int* cursor    = (int*)ws;       ws += (size_t)NBUCK * 4;

    const int BLK = 256;

    (void)hipMemsetAsync(bucketCnt, 0, (size_t)NBUCK * sizeof(int), stream);
    (void)hipMemsetAsync(rpe, 0, sizeof(int), stream);   // rpe[0] = 0
    (void)hipMemsetAsync(out_m, 0, (size_t)MEDNUM * FEATDIM * sizeof(float), stream);

    count_buckets_kernel<<<512, BLK, 0, stream>>>(a1r, a2r, bucketCnt);
    scan_buckets_kernel<<<1, BLK, 0, stream>>>(bucketCnt, bucketOff, cursor);
    lvl1_scatter_kernel<<<L1_BLOCKS, L1_THREADS, 0, stream>>>(
        a1r, a1c, a1v, a2r, a2c, a2v, cursor, l1cols, l1vals);
    lvl2_sort_kernel<<<NBUCK, BLK, 0, stream>>>(l1cols, l1vals, bucketOff,
                                                binned, rpe);

    // lvl1 dead now; regionB becomes fp16 embeddings
    convert_emb_kernel<<<(TOT8 + BLK - 1) / BLK, BLK, 0, stream>>>(
        dE, mE, pE, emb1, emb2);

    // single fused launch over both graphs
    int nrows = N1 + N2;   // 130000
    fused_gcn_kernel<<<(nrows + 3) / 4, BLK, 0, stream>>>(
        rpe, binned, emb1, emb2, inter, out_d, out_p, out_m);
}

// Round 13
// 329.958 us; speedup vs baseline: 1.3510x; 1.3510x over previous
//
#include <hip/hip_runtime.h>
#include <hip/hip_fp16.h>

#define DIAGNUM 50000
#define MEDNUM  20000
#define PRONUM  40000
#define FEATDIM 128
#define N1 (DIAGNUM + MEDNUM)   // 70000
#define N2 (PRONUM + MEDNUM)    // 60000
#define NNZ1 1120000
#define NNZ2 960000
#define NTOT (2 * N1 + 2 * N2)            // 260000 concatenated rows
#define NNZTOT (2 * NNZ1 + 2 * NNZ2)      // 4160000 concatenated edges
#define NBUCK ((NTOT + 255) >> 8)         // 1016 buckets of 256 rows
#define L1_THREADS 512
#define L1_CHUNK 8192
#define L1_ITERS (L1_CHUNK / L1_THREADS)  // 16
#define L1_BLOCKS ((NNZTOT + L1_CHUNK - 1) / L1_CHUNK)   // 508

typedef unsigned short ushort_t;
typedef float f32x4 __attribute__((ext_vector_type(4)));

// concatenated row index for edge i
__device__ __forceinline__ int edge_idx(int i, const int* __restrict__ a1r,
                                        const int* __restrict__ a2r) {
    if (i < 2 * NNZ1) {
        return ((i < NNZ1) ? 0 : N1) + __builtin_nontemporal_load(a1r + i);
    } else {
        int j = i - 2 * NNZ1;
        return 2 * N1 + ((j < NNZ2) ? 0 : N2) + __builtin_nontemporal_load(a2r + j);
    }
}

// ---------------- bucket count ----------------
__global__ __launch_bounds__(256) void count_buckets_kernel(
        const int* __restrict__ a1r, const int* __restrict__ a2r,
        int* __restrict__ bucketCnt) {
    __shared__ int lh[NBUCK];
    for (int b = threadIdx.x; b < NBUCK; b += 256) lh[b] = 0;
    __syncthreads();
    int stride = gridDim.x * 256;
    for (int i = blockIdx.x * 256 + threadIdx.x; i < NNZTOT; i += stride)
        atomicAdd(&lh[edge_idx(i, a1r, a2r) >> 8], 1);
    __syncthreads();
    for (int b = threadIdx.x; b < NBUCK; b += 256) {
        int h = lh[b];
        if (h) atomicAdd(&bucketCnt[b], h);
    }
}

// ---------------- exclusive scan of bucket counts (single block) ----------------
__global__ __launch_bounds__(256) void scan_buckets_kernel(
        const int* __restrict__ bucketCnt, int* __restrict__ bucketOff,
        int* __restrict__ cursor) {
    __shared__ int s[256];
    int t = threadIdx.x;
    int vals[4];
    int sum = 0;
#pragma unroll
    for (int k = 0; k < 4; k++) {
        int b = t * 4 + k;
        vals[k] = (b < NBUCK) ? bucketCnt[b] : 0;
        sum += vals[k];
    }
    s[t] = sum;
    __syncthreads();
    for (int off = 1; off < 256; off <<= 1) {
        int y = (t >= off) ? s[t - off] : 0;
        __syncthreads();
        s[t] += y;
        __syncthreads();
    }
    int run = s[t] - sum;
#pragma unroll
    for (int k = 0; k < 4; k++) {
        int b = t * 4 + k;
        if (b < NBUCK) {
            bucketOff[b] = run;
            cursor[b] = run;
            run += vals[k];
        }
    }
    if (t == 255) bucketOff[NBUCK] = run;   // == NNZTOT
}

// ---------------- level-1 scatter into coarse buckets ----------------
// 512 threads x 8192-edge chunks; row indices cached in registers across
// sweeps. Record split: cols word (row_local<<17)|col (4 B) + fp16 val (2 B).
__global__ __launch_bounds__(L1_THREADS) void lvl1_scatter_kernel(
        const int* __restrict__ a1r, const int* __restrict__ a1c,
        const float* __restrict__ a1v,
        const int* __restrict__ a2r, const int* __restrict__ a2c,
        const float* __restrict__ a2v,
        int* __restrict__ cursor,
        int* __restrict__ l1cols, ushort_t* __restrict__ l1vals) {
    __shared__ int lh[NBUCK];
    for (int b = threadIdx.x; b < NBUCK; b += L1_THREADS) lh[b] = 0;
    __syncthreads();
    int base = blockIdx.x * L1_CHUNK;
    int end  = min(base + L1_CHUNK, NNZTOT);
    int idxv[L1_ITERS];
    // sweep 1: block-local bucket histogram (cache idx)
    {
        int it = 0;
        for (int i = base + threadIdx.x; i < end; i += L1_THREADS, it++) {
            int idx = edge_idx(i, a1r, a2r);
            idxv[it] = idx;
            atomicAdd(&lh[idx >> 8], 1);
        }
    }
    __syncthreads();
    // reserve spans: lh[b] becomes this block's rolling global cursor
    for (int b = threadIdx.x; b < NBUCK; b += L1_THREADS) {
        int h = lh[b];
        lh[b] = h ? atomicAdd(&cursor[b], h) : 0;
    }
    __syncthreads();
    // sweep 2: write records (col/val only; idx from registers)
    {
        int it = 0;
        for (int i = base + threadIdx.x; i < end; i += L1_THREADS, it++) {
            int col;
            float val;
            if (i < 2 * NNZ1) {
                col = __builtin_nontemporal_load(a1c + i);
                val = __builtin_nontemporal_load(a1v + i);
            } else {
                int j = i - 2 * NNZ1;
                col = __builtin_nontemporal_load(a2c + j);
                val = __builtin_nontemporal_load(a2v + j);
            }
            int idx = idxv[it];
            int pos = atomicAdd(&lh[idx >> 8], 1);
            l1cols[pos] = ((idx & 255) << 17) | col;
            l1vals[pos] = __half_as_ushort(__float2half(val));
        }
    }
}

// ---------------- level-2 sort within bucket (one block per bucket) ----------------
// Block exclusively owns its ~16 KB destination range -> clean full-line writes.
// Final record: 4 B = (fp16(val) << 17) | col  (val in [0,1): sign=0, 15 bits).
// Also writes rpe[idx+1] = row end offsets.
__global__ __launch_bounds__(256) void lvl2_sort_kernel(
        const int* __restrict__ l1cols, const ushort_t* __restrict__ l1vals,
        const int* __restrict__ bucketOff,
        int* __restrict__ binned, int* __restrict__ rpe) {
    __shared__ int cnt[256];
    __shared__ int sc[256];
    int b = blockIdx.x;
    int t = threadIdx.x;
    int s0 = bucketOff[b];
    int e0 = bucketOff[b + 1];
    cnt[t] = 0;
    __syncthreads();
    for (int k = s0 + t; k < e0; k += 256)
        atomicAdd(&cnt[__builtin_nontemporal_load(l1cols + k) >> 17], 1);
    __syncthreads();
    int v = cnt[t];
    sc[t] = v;
    __syncthreads();
    for (int off = 1; off < 256; off <<= 1) {
        int y = (t >= off) ? sc[t - off] : 0;
        __syncthreads();
        sc[t] += y;
        __syncthreads();
    }
    int incl = sc[t];
    int excl = incl - v;
    int idx = (b << 8) + t;
    if (idx < NTOT) rpe[idx + 1] = s0 + incl;
    cnt[t] = excl;   // repurpose as local cursor
    __syncthreads();
    for (int k = s0 + t; k < e0; k += 256) {
        int c  = __builtin_nontemporal_load(l1cols + k);
        unsigned hv = __builtin_nontemporal_load(l1vals + k);
        int rl  = c >> 17;
        int col = c & 0x1FFFF;
        int pos = atomicAdd(&cnt[rl], 1);
        binned[s0 + pos] = (int)((hv << 17) | (unsigned)col);
    }
}

// ---------------- fp16 embedding conversion (unified per-graph layouts) ----------------
// emb1 = [dE; mE] (N1 x 128), emb2 = [pE; mE] (N2 x 128); med rows duplicated.
#define TOT8 ((DIAGNUM + MEDNUM + PRONUM) * (FEATDIM / 8))   // 1,760,000

__device__ __forceinline__ ushort_t f2h(float x) {
    return __half_as_ushort(__float2half(x));
}

__global__ __launch_bounds__(256) void convert_emb_kernel(
        const float* __restrict__ dE, const float* __restrict__ mE,
        const float* __restrict__ pE,
        ushort_t* __restrict__ emb1, ushort_t* __restrict__ emb2) {
    int t8 = blockIdx.x * 256 + threadIdx.x;
    if (t8 >= TOT8) return;
    long flat = (long)t8 * 8;
    const float* src;
    ushort_t* dst;
    ushort_t* dst2 = nullptr;
    if (flat < (long)DIAGNUM * FEATDIM) {
        src = dE + flat;
        dst = emb1 + flat;
    } else if (flat < (long)(DIAGNUM + MEDNUM) * FEATDIM) {
        long o = flat - (long)DIAGNUM * FEATDIM;
        src = mE + o;
        dst  = emb1 + (long)DIAGNUM * FEATDIM + o;
        dst2 = emb2 + (long)PRONUM * FEATDIM + o;
    } else {
        long o = flat - (long)(DIAGNUM + MEDNUM) * FEATDIM;
        src = pE + o;
        dst = emb2 + o;
    }
    float4 a = *reinterpret_cast<const float4*>(src);
    float4 b = *reinterpret_cast<const float4*>(src + 4);
    int4 w;
    w.x = (int)((unsigned)f2h(a.x) | ((unsigned)f2h(a.y) << 16));
    w.y = (int)((unsigned)f2h(a.z) | ((unsigned)f2h(a.w) << 16));
    w.z = (int)((unsigned)f2h(b.x) | ((unsigned)f2h(b.y) << 16));
    w.w = (int)((unsigned)f2h(b.z) | ((unsigned)f2h(b.w) << 16));
    *reinterpret_cast<int4*>(dst) = w;
    if (dst2) *reinterpret_cast<int4*>(dst2) = w;
}

// ---------------- fused GCN row kernel (quarter-wave fp16 gather, 2x unroll) ----------------
// 16 lanes x 16 B (8 fp16) per edge, 8 edges in flight per wave.

__device__ __forceinline__ void fma8(float acc[8], float v, int4 h) {
    union U { int4 i; __half2 h2[4]; } u;
    u.i = h;
#pragma unroll
    for (int j = 0; j < 4; j++) {
        float2 f = __half22float2(u.h2[j]);
        acc[2 * j]     = fmaf(v, f.x, acc[2 * j]);
        acc[2 * j + 1] = fmaf(v, f.y, acc[2 * j + 1]);
    }
}

__device__ __forceinline__ float rec_val(unsigned rec) {
    return __half2float(__ushort_as_half((unsigned short)(rec >> 17)));
}

__device__ __forceinline__ void gather8(int s, int e,
                                        const int* __restrict__ binned,
                                        int q, int sub16,
                                        const ushort_t* __restrict__ emb,
                                        float acc[8]) {
    int k = s + q;
    for (; k + 4 < e; k += 8) {
        unsigned r0 = (unsigned)binned[k];
        unsigned r1 = (unsigned)binned[k + 4];
        const int4* b0 = reinterpret_cast<const int4*>(emb + ((size_t)(r0 & 0x1FFFFu) << 7));
        const int4* b1 = reinterpret_cast<const int4*>(emb + ((size_t)(r1 & 0x1FFFFu) << 7));
        int4 h0 = b0[sub16];
        int4 h1 = b1[sub16];
        fma8(acc, rec_val(r0), h0);
        fma8(acc, rec_val(r1), h1);
    }
    for (; k < e; k += 4) {
        unsigned r0 = (unsigned)binned[k];
        const int4* b0 = reinterpret_cast<const int4*>(emb + ((size_t)(r0 & 0x1FFFFu) << 7));
        int4 h0 = b0[sub16];
        fma8(acc, rec_val(r0), h0);
    }
}

__device__ __forceinline__ void nt_store4(float* p, float a, float b,
                                          float c, float d) {
    f32x4 v = {a, b, c, d};
    __builtin_nontemporal_store(v, reinterpret_cast<f32x4*>(p));
}

// One 64-lane wave per output row of ONE graph.
// graph==0 (graph2): med rows -> out_m = (1-t)*res (pure write)
// graph==1 (graph1): med rows -> out_m += t*res    (after graph2 launch)
__global__ __launch_bounds__(256) void fused_gcn_kernel(
        const int* __restrict__ rpe,
        const int* __restrict__ binned,
        const ushort_t* __restrict__ emb,   // unified layout for this graph
        const float* __restrict__ inter,
        float* __restrict__ out_d, float* __restrict__ out_p,
        float* __restrict__ out_m, int graph) {
    int gtid = blockIdx.x * blockDim.x + threadIdx.x;
    int w     = gtid >> 6;
    int lane  = gtid & 63;
    int q     = lane >> 4;
    int sub16 = lane & 15;

    const int *rpA, *rpB;
    int nrows;
    if (graph) { nrows = N1; rpA = rpe + w; rpB = rpe + N1 + w; }
    else       { nrows = N2; rpA = rpe + 2 * N1 + w; rpB = rpe + 2 * N1 + N2 + w; }
    if (w >= nrows) return;

    float aA[8] = {0, 0, 0, 0, 0, 0, 0, 0};
    float aB[8] = {0, 0, 0, 0, 0, 0, 0, 0};
    gather8(rpA[0], rpA[1], binned, q, sub16, emb, aA);
    gather8(rpB[0], rpB[1], binned, q, sub16, emb, aB);

    // reduce the 4 quarters
#pragma unroll
    for (int j = 0; j < 8; j++) {
        aA[j] += __shfl_xor(aA[j], 16);
        aA[j] += __shfl_xor(aA[j], 32);
        aB[j] += __shfl_xor(aB[j], 16);
        aB[j] += __shfl_xor(aB[j], 32);
    }

    if (lane >= 16) return;

    float res[8];
#pragma unroll
    for (int j = 0; j < 8; j++)
        res[j] = 2.f * (fmaxf(aA[j], 0.f) + fmaxf(aB[j], 0.f));

    if (graph) {
        if (w < DIAGNUM) {
            float* dst = out_d + (size_t)w * FEATDIM + sub16 * 8;
            nt_store4(dst,     res[0], res[1], res[2], res[3]);
            nt_store4(dst + 4, res[4], res[5], res[6], res[7]);
        } else {
            float t = *inter;
            float* dst = out_m + (size_t)(w - DIAGNUM) * FEATDIM + sub16 * 8;
            float4 o0 = *reinterpret_cast<float4*>(dst);
            float4 o1 = *reinterpret_cast<float4*>(dst + 4);
            o0.x = fmaf(t, res[0], o0.x); o0.y = fmaf(t, res[1], o0.y);
            o0.z = fmaf(t, res[2], o0.z); o0.w = fmaf(t, res[3], o0.w);
            o1.x = fmaf(t, res[4], o1.x); o1.y = fmaf(t, res[5], o1.y);
            o1.z = fmaf(t, res[6], o1.z); o1.w = fmaf(t, res[7], o1.w);
            *reinterpret_cast<float4*>(dst)     = o0;
            *reinterpret_cast<float4*>(dst + 4) = o1;
        }
    } else {
        if (w < PRONUM) {
            float* dst = out_p + (size_t)w * FEATDIM + sub16 * 8;
            nt_store4(dst,     res[0], res[1], res[2], res[3]);
            nt_store4(dst + 4, res[4], res[5], res[6], res[7]);
        } else {
            float sc = 1.0f - *inter;
            float* dst = out_m + (size_t)(w - PRONUM) * FEATDIM + sub16 * 8;
            float4 v0 = make_float4(sc * res[0], sc * res[1], sc * res[2], sc * res[3]);
            float4 v1 = make_float4(sc * res[4], sc * res[5], sc * res[6], sc * res[7]);
            *reinterpret_cast<float4*>(dst)     = v0;
            *reinterpret_cast<float4*>(dst + 4) = v1;
        }
    }
}

// ---------------- host orchestration ----------------

extern "C" void kernel_launch(void* const* d_in, const int* in_sizes, int n_in,
                              void* d_out, int out_size, void* d_ws, size_t ws_size,
                              hipStream_t stream) {
    const int*   a1r = (const int*)d_in[0];
    const int*   a1c = (const int*)d_in[1];
    const float* a1v = (const float*)d_in[2];
    const int*   a2r = (const int*)d_in[3];
    const int*   a2c = (const int*)d_in[4];
    const float* a2v = (const float*)d_in[5];
    const float* dE  = (const float*)d_in[6];
    const float* mE  = (const float*)d_in[7];
    const float* pE  = (const float*)d_in[8];
    const float* inter = (const float*)d_in[9];

    float* out   = (float*)d_out;
    float* out_m = out;                               // 20000*128
    float* out_d = out + (size_t)MEDNUM * FEATDIM;    // 50000*128
    float* out_p = out_d + (size_t)DIAGNUM * FEATDIM; // 40000*128

    // ws layout (~51 MB). regionB is time-shared: lvl1 split records (sort
    // phase: cols 16.64 MB + vals 8.32 MB), then fp16 unified embeddings
    // (emb1 17.92 + emb2 15.36 = 33.28 MB) — lvl1 dead after lvl2_sort.
    char* ws = (char*)d_ws;
    int* binned = (int*)ws;          ws += (size_t)NNZTOT * 4;          // 16.64 MB
    char* regionB = ws;              ws += (size_t)NNZTOT * 8;          // 33.28 MB
    int*      l1cols = (int*)regionB;
    ushort_t* l1vals = (ushort_t*)(regionB + (size_t)NNZTOT * 4);
    ushort_t* emb1 = (ushort_t*)regionB;                    // N1*128 fp16
    ushort_t* emb2 = emb1 + (size_t)N1 * FEATDIM;           // N2*128 fp16
    int* rpe       = (int*)ws;       ws += (((size_t)(NTOT + 1) * 4 + 15) & ~15ull);
    int* bucketCnt = (int*)ws;       ws += (size_t)NBUCK * 4;
    int* bucketOff = (int*)ws;       ws += (size_t)(NBUCK + 1) * 4;
    int* cursor    = (int*)ws;       ws += (size_t)NBUCK * 4;

    const int BLK = 256;

    (void)hipMemsetAsync(bucketCnt, 0, (size_t)NBUCK * sizeof(int), stream);
    (void)hipMemsetAsync(rpe, 0, sizeof(int), stream);   // rpe[0] = 0

    count_buckets_kernel<<<512, BLK, 0, stream>>>(a1r, a2r, bucketCnt);
    scan_buckets_kernel<<<1, BLK, 0, stream>>>(bucketCnt, bucketOff, cursor);
    lvl1_scatter_kernel<<<L1_BLOCKS, L1_THREADS, 0, stream>>>(
        a1r, a1c, a1v, a2r, a2c, a2v, cursor, l1cols, l1vals);
    lvl2_sort_kernel<<<NBUCK, BLK, 0, stream>>>(l1cols, l1vals, bucketOff,
                                                binned, rpe);

    // lvl1 dead now; regionB becomes fp16 embeddings
    convert_emb_kernel<<<(TOT8 + BLK - 1) / BLK, BLK, 0, stream>>>(
        dE, mE, pE, emb1, emb2);

    // graph 2 first (writes out_m pure), then graph 1 (accumulates out_m)
    fused_gcn_kernel<<<(N2 + 3) / 4, BLK, 0, stream>>>(
        rpe, binned, emb2, inter, out_d, out_p, out_m, 0);
    fused_gcn_kernel<<<(N1 + 3) / 4, BLK, 0, stream>>>(
        rpe, binned, emb1, inter, out_d, out_p, out_m, 1);
}

// Round 14
// 316.851 us; speedup vs baseline: 1.4069x; 1.0414x over previous
//
#include <hip/hip_runtime.h>
#include <hip/hip_fp16.h>

#define DIAGNUM 50000
#define MEDNUM  20000
#define PRONUM  40000
#define FEATDIM 128
#define N1 (DIAGNUM + MEDNUM)   // 70000
#define N2 (PRONUM + MEDNUM)    // 60000
#define NNZ1 1120000
#define NNZ2 960000
#define NTOT (2 * N1 + 2 * N2)            // 260000 concatenated rows
#define NNZTOT (2 * NNZ1 + 2 * NNZ2)      // 4160000 concatenated edges
#define NBUCK ((NTOT + 255) >> 8)         // 1016 buckets of 256 rows
#define L1_THREADS 512
#define L1_CHUNK 4096
#define L1_ITERS (L1_CHUNK / L1_THREADS)  // 8
#define L1_BLOCKS ((NNZTOT + L1_CHUNK - 1) / L1_CHUNK)   // 1016

typedef unsigned short ushort_t;
typedef float f32x4 __attribute__((ext_vector_type(4)));

// concatenated row index for edge i
__device__ __forceinline__ int edge_idx(int i, const int* __restrict__ a1r,
                                        const int* __restrict__ a2r) {
    if (i < 2 * NNZ1) {
        return ((i < NNZ1) ? 0 : N1) + __builtin_nontemporal_load(a1r + i);
    } else {
        int j = i - 2 * NNZ1;
        return 2 * N1 + ((j < NNZ2) ? 0 : N2) + __builtin_nontemporal_load(a2r + j);
    }
}

// ---------------- bucket count ----------------
__global__ __launch_bounds__(256) void count_buckets_kernel(
        const int* __restrict__ a1r, const int* __restrict__ a2r,
        int* __restrict__ bucketCnt) {
    __shared__ int lh[NBUCK];
    for (int b = threadIdx.x; b < NBUCK; b += 256) lh[b] = 0;
    __syncthreads();
    int stride = gridDim.x * 256;
    for (int i = blockIdx.x * 256 + threadIdx.x; i < NNZTOT; i += stride)
        atomicAdd(&lh[edge_idx(i, a1r, a2r) >> 8], 1);
    __syncthreads();
    for (int b = threadIdx.x; b < NBUCK; b += 256) {
        int h = lh[b];
        if (h) atomicAdd(&bucketCnt[b], h);
    }
}

// ---------------- exclusive scan of bucket counts (single block) ----------------
__global__ __launch_bounds__(256) void scan_buckets_kernel(
        const int* __restrict__ bucketCnt, int* __restrict__ bucketOff,
        int* __restrict__ cursor) {
    __shared__ int s[256];
    int t = threadIdx.x;
    int vals[4];
    int sum = 0;
#pragma unroll
    for (int k = 0; k < 4; k++) {
        int b = t * 4 + k;
        vals[k] = (b < NBUCK) ? bucketCnt[b] : 0;
        sum += vals[k];
    }
    s[t] = sum;
    __syncthreads();
    for (int off = 1; off < 256; off <<= 1) {
        int y = (t >= off) ? s[t - off] : 0;
        __syncthreads();
        s[t] += y;
        __syncthreads();
    }
    int run = s[t] - sum;
#pragma unroll
    for (int k = 0; k < 4; k++) {
        int b = t * 4 + k;
        if (b < NBUCK) {
            bucketOff[b] = run;
            cursor[b] = run;
            run += vals[k];
        }
    }
    if (t == 255) bucketOff[NBUCK] = run;   // == NNZTOT
}

// ---------------- level-1 scatter into coarse buckets ----------------
// 512 threads x 4096-edge chunks (1016 blocks, ~4/CU for latency hiding);
// row indices cached in registers across sweeps; single 8 B record store.
// record: .x = (row_local << 17) | col   (row_local 8b, col 17b), .y = val bits
__global__ __launch_bounds__(L1_THREADS) void lvl1_scatter_kernel(
        const int* __restrict__ a1r, const int* __restrict__ a1c,
        const float* __restrict__ a1v,
        const int* __restrict__ a2r, const int* __restrict__ a2c,
        const float* __restrict__ a2v,
        int* __restrict__ cursor, int2* __restrict__ lvl1) {
    __shared__ int lh[NBUCK];
    for (int b = threadIdx.x; b < NBUCK; b += L1_THREADS) lh[b] = 0;
    __syncthreads();
    int base = blockIdx.x * L1_CHUNK;
    int end  = min(base + L1_CHUNK, NNZTOT);
    int idxv[L1_ITERS];
    // sweep 1: block-local bucket histogram (cache idx)
    {
        int it = 0;
        for (int i = base + threadIdx.x; i < end; i += L1_THREADS, it++) {
            int idx = edge_idx(i, a1r, a2r);
            idxv[it] = idx;
            atomicAdd(&lh[idx >> 8], 1);
        }
    }
    __syncthreads();
    // reserve spans: lh[b] becomes this block's rolling global cursor
    for (int b = threadIdx.x; b < NBUCK; b += L1_THREADS) {
        int h = lh[b];
        lh[b] = h ? atomicAdd(&cursor[b], h) : 0;
    }
    __syncthreads();
    // sweep 2: write records (col/val only; idx from registers)
    {
        int it = 0;
        for (int i = base + threadIdx.x; i < end; i += L1_THREADS, it++) {
            int col;
            float val;
            if (i < 2 * NNZ1) {
                col = __builtin_nontemporal_load(a1c + i);
                val = __builtin_nontemporal_load(a1v + i);
            } else {
                int j = i - 2 * NNZ1;
                col = __builtin_nontemporal_load(a2c + j);
                val = __builtin_nontemporal_load(a2v + j);
            }
            int idx = idxv[it];
            int pos = atomicAdd(&lh[idx >> 8], 1);
            lvl1[pos] = make_int2(((idx & 255) << 17) | col, __float_as_int(val));
        }
    }
}

// ---------------- level-2 sort within bucket (one block per bucket) ----------------
// Block exclusively owns its ~16 KB destination range -> clean full-line writes.
// Final record: 4 B = (fp16(val) << 17) | col  (val in [0,1): sign=0, 15 bits).
// Also writes rpe[idx+1] = row end offsets.
__global__ __launch_bounds__(256) void lvl2_sort_kernel(
        const int2* __restrict__ lvl1, const int* __restrict__ bucketOff,
        int* __restrict__ binned, int* __restrict__ rpe) {
    __shared__ int cnt[256];
    __shared__ int sc[256];
    int b = blockIdx.x;
    int t = threadIdx.x;
    int s0 = bucketOff[b];
    int e0 = bucketOff[b + 1];
    cnt[t] = 0;
    __syncthreads();
    for (int k = s0 + t; k < e0; k += 256)
        atomicAdd(&cnt[__builtin_nontemporal_load(&lvl1[k].x) >> 17], 1);
    __syncthreads();
    int v = cnt[t];
    sc[t] = v;
    __syncthreads();
    for (int off = 1; off < 256; off <<= 1) {
        int y = (t >= off) ? sc[t - off] : 0;
        __syncthreads();
        sc[t] += y;
        __syncthreads();
    }
    int incl = sc[t];
    int excl = incl - v;
    int idx = (b << 8) + t;
    if (idx < NTOT) rpe[idx + 1] = s0 + incl;
    cnt[t] = excl;   // repurpose as local cursor
    __syncthreads();
    for (int k = s0 + t; k < e0; k += 256) {
        int2 rec = lvl1[k];
        int rl  = rec.x >> 17;
        int col = rec.x & 0x1FFFF;
        unsigned hv = __half_as_ushort(__float2half(__int_as_float(rec.y)));
        int pos = atomicAdd(&cnt[rl], 1);
        binned[s0 + pos] = (int)((hv << 17) | (unsigned)col);
    }
}

// ---------------- fp16 embedding conversion (unified per-graph layouts) ----------------
// emb1 = [dE; mE] (N1 x 128), emb2 = [pE; mE] (N2 x 128); med rows duplicated.
#define TOT8 ((DIAGNUM + MEDNUM + PRONUM) * (FEATDIM / 8))   // 1,760,000

__device__ __forceinline__ ushort_t f2h(float x) {
    return __half_as_ushort(__float2half(x));
}

__global__ __launch_bounds__(256) void convert_emb_kernel(
        const float* __restrict__ dE, const float* __restrict__ mE,
        const float* __restrict__ pE,
        ushort_t* __restrict__ emb1, ushort_t* __restrict__ emb2) {
    int t8 = blockIdx.x * 256 + threadIdx.x;
    if (t8 >= TOT8) return;
    long flat = (long)t8 * 8;
    const float* src;
    ushort_t* dst;
    ushort_t* dst2 = nullptr;
    if (flat < (long)DIAGNUM * FEATDIM) {
        src = dE + flat;
        dst = emb1 + flat;
    } else if (flat < (long)(DIAGNUM + MEDNUM) * FEATDIM) {
        long o = flat - (long)DIAGNUM * FEATDIM;
        src = mE + o;
        dst  = emb1 + (long)DIAGNUM * FEATDIM + o;
        dst2 = emb2 + (long)PRONUM * FEATDIM + o;
    } else {
        long o = flat - (long)(DIAGNUM + MEDNUM) * FEATDIM;
        src = pE + o;
        dst = emb2 + o;
    }
    float4 a = *reinterpret_cast<const float4*>(src);
    float4 b = *reinterpret_cast<const float4*>(src + 4);
    int4 w;
    w.x = (int)((unsigned)f2h(a.x) | ((unsigned)f2h(a.y) << 16));
    w.y = (int)((unsigned)f2h(a.z) | ((unsigned)f2h(a.w) << 16));
    w.z = (int)((unsigned)f2h(b.x) | ((unsigned)f2h(b.y) << 16));
    w.w = (int)((unsigned)f2h(b.z) | ((unsigned)f2h(b.w) << 16));
    *reinterpret_cast<int4*>(dst) = w;
    if (dst2) *reinterpret_cast<int4*>(dst2) = w;
}

// ---------------- fused GCN row kernel ----------------
// Quarter-wave fp16 gather: 16 lanes x 16 B (8 fp16) per edge.
// Dual-stream: adjacency A and B records issued together -> 4 gathers in
// flight per lane (deeper memory-level parallelism on the L2-miss path).

__device__ __forceinline__ void fma8(float acc[8], float v, int4 h) {
    union U { int4 i; __half2 h2[4]; } u;
    u.i = h;
#pragma unroll
    for (int j = 0; j < 4; j++) {
        float2 f = __half22float2(u.h2[j]);
        acc[2 * j]     = fmaf(v, f.x, acc[2 * j]);
        acc[2 * j + 1] = fmaf(v, f.y, acc[2 * j + 1]);
    }
}

__device__ __forceinline__ float rec_val(unsigned rec) {
    return __half2float(__ushort_as_half((unsigned short)(rec >> 17)));
}

__device__ __forceinline__ const int4* emb_row(unsigned rec,
                                               const ushort_t* __restrict__ emb) {
    return reinterpret_cast<const int4*>(emb + ((size_t)(rec & 0x1FFFFu) << 7));
}

// drain: single stream from k (already q-offset) to e
__device__ __forceinline__ void gather_drain(int k, int e,
                                             const int* __restrict__ binned,
                                             int sub16,
                                             const ushort_t* __restrict__ emb,
                                             float acc[8]) {
    for (; k + 4 < e; k += 8) {
        unsigned r0 = (unsigned)binned[k];
        unsigned r1 = (unsigned)binned[k + 4];
        int4 h0 = emb_row(r0, emb)[sub16];
        int4 h1 = emb_row(r1, emb)[sub16];
        fma8(acc, rec_val(r0), h0);
        fma8(acc, rec_val(r1), h1);
    }
    for (; k < e; k += 4) {
        unsigned r0 = (unsigned)binned[k];
        int4 h0 = emb_row(r0, emb)[sub16];
        fma8(acc, rec_val(r0), h0);
    }
}

__device__ __forceinline__ void nt_store4(float* p, float a, float b,
                                          float c, float d) {
    f32x4 v = {a, b, c, d};
    __builtin_nontemporal_store(v, reinterpret_cast<f32x4*>(p));
}

// One 64-lane wave per output row of ONE graph.
// graph==0 (graph2): med rows -> out_m = (1-t)*res (pure write)
// graph==1 (graph1): med rows -> out_m += t*res    (after graph2 launch)
__global__ __launch_bounds__(256) void fused_gcn_kernel(
        const int* __restrict__ rpe,
        const int* __restrict__ binned,
        const ushort_t* __restrict__ emb,   // unified layout for this graph
        const float* __restrict__ inter,
        float* __restrict__ out_d, float* __restrict__ out_p,
        float* __restrict__ out_m, int graph) {
    int gtid = blockIdx.x * blockDim.x + threadIdx.x;
    int w     = gtid >> 6;
    int lane  = gtid & 63;
    int q     = lane >> 4;
    int sub16 = lane & 15;

    const int *rpA, *rpB;
    int nrows;
    if (graph) { nrows = N1; rpA = rpe + w; rpB = rpe + N1 + w; }
    else       { nrows = N2; rpA = rpe + 2 * N1 + w; rpB = rpe + 2 * N1 + N2 + w; }
    if (w >= nrows) return;

    float aA[8] = {0, 0, 0, 0, 0, 0, 0, 0};
    float aB[8] = {0, 0, 0, 0, 0, 0, 0, 0};

    int kA = rpA[0] + q, eA = rpA[1];
    int kB = rpB[0] + q, eB = rpB[1];

    // dual-stream main loop: 4 records in flight (2 per adjacency)
    while (kA + 4 < eA && kB + 4 < eB) {
        unsigned rA0 = (unsigned)binned[kA];
        unsigned rA1 = (unsigned)binned[kA + 4];
        unsigned rB0 = (unsigned)binned[kB];
        unsigned rB1 = (unsigned)binned[kB + 4];
        int4 hA0 = emb_row(rA0, emb)[sub16];
        int4 hA1 = emb_row(rA1, emb)[sub16];
        int4 hB0 = emb_row(rB0, emb)[sub16];
        int4 hB1 = emb_row(rB1, emb)[sub16];
        fma8(aA, rec_val(rA0), hA0);
        fma8(aA, rec_val(rA1), hA1);
        fma8(aB, rec_val(rB0), hB0);
        fma8(aB, rec_val(rB1), hB1);
        kA += 8; kB += 8;
    }
    gather_drain(kA, eA, binned, sub16, emb, aA);
    gather_drain(kB, eB, binned, sub16, emb, aB);

    // reduce the 4 quarters
#pragma unroll
    for (int j = 0; j < 8; j++) {
        aA[j] += __shfl_xor(aA[j], 16);
        aA[j] += __shfl_xor(aA[j], 32);
        aB[j] += __shfl_xor(aB[j], 16);
        aB[j] += __shfl_xor(aB[j], 32);
    }

    if (lane >= 16) return;

    float res[8];
#pragma unroll
    for (int j = 0; j < 8; j++)
        res[j] = 2.f * (fmaxf(aA[j], 0.f) + fmaxf(aB[j], 0.f));

    if (graph) {
        if (w < DIAGNUM) {
            float* dst = out_d + (size_t)w * FEATDIM + sub16 * 8;
            nt_store4(dst,     res[0], res[1], res[2], res[3]);
            nt_store4(dst + 4, res[4], res[5], res[6], res[7]);
        } else {
            float t = *inter;
            float* dst = out_m + (size_t)(w - DIAGNUM) * FEATDIM + sub16 * 8;
            float4 o0 = *reinterpret_cast<float4*>(dst);
            float4 o1 = *reinterpret_cast<float4*>(dst + 4);
            o0.x = fmaf(t, res[0], o0.x); o0.y = fmaf(t, res[1], o0.y);
            o0.z = fmaf(t, res[2], o0.z); o0.w = fmaf(t, res[3], o0.w);
            o1.x = fmaf(t, res[4], o1.x); o1.y = fmaf(t, res[5], o1.y);
            o1.z = fmaf(t, res[6], o1.z); o1.w = fmaf(t, res[7], o1.w);
            *reinterpret_cast<float4*>(dst)     = o0;
            *reinterpret_cast<float4*>(dst + 4) = o1;
        }
    } else {
        if (w < PRONUM) {
            float* dst = out_p + (size_t)w * FEATDIM + sub16 * 8;
            nt_store4(dst,     res[0], res[1], res[2], res[3]);
            nt_store4(dst + 4, res[4], res[5], res[6], res[7]);
        } else {
            float sc = 1.0f - *inter;
            float* dst = out_m + (size_t)(w - PRONUM) * FEATDIM + sub16 * 8;
            float4 v0 = make_float4(sc * res[0], sc * res[1], sc * res[2], sc * res[3]);
            float4 v1 = make_float4(sc * res[4], sc * res[5], sc * res[6], sc * res[7]);
            *reinterpret_cast<float4*>(dst)     = v0;
            *reinterpret_cast<float4*>(dst + 4) = v1;
        }
    }
}

// ---------------- host orchestration ----------------

extern "C" void kernel_launch(void* const* d_in, const int* in_sizes, int n_in,
                              void* d_out, int out_size, void* d_ws, size_t ws_size,
                              hipStream_t stream) {
    const int*   a1r = (const int*)d_in[0];
    const int*   a1c = (const int*)d_in[1];
    const float* a1v = (const float*)d_in[2];
    const int*   a2r = (const int*)d_in[3];
    const int*   a2c = (const int*)d_in[4];
    const float* a2v = (const float*)d_in[5];
    const float* dE  = (const float*)d_in[6];
    const float* mE  = (const float*)d_in[7];
    const float* pE  = (const float*)d_in[8];
    const float* inter = (const float*)d_in[9];

    float* out   = (float*)d_out;
    float* out_m = out;                               // 20000*128
    float* out_d = out + (size_t)MEDNUM * FEATDIM;    // 50000*128
    float* out_p = out_d + (size_t)DIAGNUM * FEATDIM; // 40000*128

    // ws layout (~51 MB). regionB is time-shared: lvl1 int2 records (sort
    // phase, 33.28 MB), then fp16 unified embeddings (emb1 17.92 + emb2
    // 15.36 = 33.28 MB) — lvl1 dead after lvl2_sort.
    char* ws = (char*)d_ws;
    int* binned = (int*)ws;          ws += (size_t)NNZTOT * 4;          // 16.64 MB
    char* regionB = ws;              ws += (size_t)NNZTOT * 8;          // 33.28 MB
    int2*     lvl1 = (int2*)regionB;
    ushort_t* emb1 = (ushort_t*)regionB;                    // N1*128 fp16
    ushort_t* emb2 = emb1 + (size_t)N1 * FEATDIM;           // N2*128 fp16
    int* rpe       = (int*)ws;       ws += (((size_t)(NTOT + 1) * 4 + 15) & ~15ull);
    int* bucketCnt = (int*)ws;       ws += (size_t)NBUCK * 4;
    int* bucketOff = (int*)ws;       ws += (size_t)(NBUCK + 1) * 4;
    int* cursor    = (int*)ws;       ws += (size_t)NBUCK * 4;

    const int BLK = 256;

    (void)hipMemsetAsync(bucketCnt, 0, (size_t)NBUCK * sizeof(int), stream);
    (void)hipMemsetAsync(rpe, 0, sizeof(int), stream);   // rpe[0] = 0

    count_buckets_kernel<<<512, BLK, 0, stream>>>(a1r, a2r, bucketCnt);
    scan_buckets_kernel<<<1, BLK, 0, stream>>>(bucketCnt, bucketOff, cursor);
    lvl1_scatter_kernel<<<L1_BLOCKS, L1_THREADS, 0, stream>>>(
        a1r, a1c, a1v, a2r, a2c, a2v, cursor, lvl1);
    lvl2_sort_kernel<<<NBUCK, BLK, 0, stream>>>(lvl1, bucketOff, binned, rpe);

    // lvl1 dead now; regionB becomes fp16 embeddings
    convert_emb_kernel<<<(TOT8 + BLK - 1) / BLK, BLK, 0, stream>>>(
        dE, mE, pE, emb1, emb2);

    // graph 2 first (writes out_m pure), then graph 1 (accumulates out_m)
    fused_gcn_kernel<<<(N2 + 3) / 4, BLK, 0, stream>>>(
        rpe, binned, emb2, inter, out_d, out_p, out_m, 0);
    fused_gcn_kernel<<<(N1 + 3) / 4, BLK, 0, stream>>>(
        rpe, binned, emb1, inter, out_d, out_p, out_m, 1);
}

// Round 15
// 242.529 us; speedup vs baseline: 1.8380x; 1.3064x over previous
//
#include <hip/hip_runtime.h>
#include <hip/hip_fp16.h>

#define DIAGNUM 50000
#define MEDNUM  20000
#define PRONUM  40000
#define FEATDIM 128
#define N1 (DIAGNUM + MEDNUM)   // 70000
#define N2 (PRONUM + MEDNUM)    // 60000
#define NNZ1 1120000
#define NNZ2 960000
#define NTOT (2 * N1 + 2 * N2)            // 260000 concatenated rows
#define NNZTOT (2 * NNZ1 + 2 * NNZ2)      // 4160000 concatenated edges
#define NBUCK ((NTOT + 511) >> 9)         // 508 buckets of 512 rows
#define CAP 8704                           // bucket capacity (mean 8192, +5.7 sigma)
#define L1_THREADS 512
#define L1_CHUNK 8192
#define L1_ITERS (L1_CHUNK / L1_THREADS)  // 16
#define L1_BLOCKS ((NNZTOT + L1_CHUNK - 1) / L1_CHUNK)   // 508

typedef unsigned short ushort_t;

// concatenated row index for edge i
__device__ __forceinline__ int edge_idx(int i, const int* __restrict__ a1r,
                                        const int* __restrict__ a2r) {
    if (i < 2 * NNZ1) {
        return ((i < NNZ1) ? 0 : N1) + __builtin_nontemporal_load(a1r + i);
    } else {
        int j = i - 2 * NNZ1;
        return 2 * N1 + ((j < NNZ2) ? 0 : N2) + __builtin_nontemporal_load(a2r + j);
    }
}

// ---------------- cursor init (bucket bases are fixed: b*CAP) ----------------
__global__ __launch_bounds__(256) void init_cursor_kernel(int* __restrict__ cursor) {
    int b = blockIdx.x * 256 + threadIdx.x;
    if (b < NBUCK) cursor[b] = b * CAP;
}

// ---------------- level-1 scatter into fixed-capacity buckets ----------------
// 512 threads x 8192-edge chunks; row indices cached in registers across
// sweeps; one global atomic per (chunk,bucket); 8 B int2 record stores in
// ~16-edge (128 B) runs.
// record: .x = (row_local << 17) | col   (row_local 9b, col 17b), .y = val bits
__global__ __launch_bounds__(L1_THREADS) void lvl1_scatter_kernel(
        const int* __restrict__ a1r, const int* __restrict__ a1c,
        const float* __restrict__ a1v,
        const int* __restrict__ a2r, const int* __restrict__ a2c,
        const float* __restrict__ a2v,
        int* __restrict__ cursor, int2* __restrict__ lvl1) {
    __shared__ int lh[NBUCK];
    for (int b = threadIdx.x; b < NBUCK; b += L1_THREADS) lh[b] = 0;
    __syncthreads();
    int base = blockIdx.x * L1_CHUNK;
    int end  = min(base + L1_CHUNK, NNZTOT);
    int idxv[L1_ITERS];
    // sweep 1: block-local bucket histogram (cache idx in registers)
    {
        int it = 0;
        for (int i = base + threadIdx.x; i < end; i += L1_THREADS, it++) {
            int idx = edge_idx(i, a1r, a2r);
            idxv[it] = idx;
            atomicAdd(&lh[idx >> 9], 1);
        }
    }
    __syncthreads();
    // reserve spans: lh[b] becomes this block's rolling global cursor
    for (int b = threadIdx.x; b < NBUCK; b += L1_THREADS) {
        int h = lh[b];
        lh[b] = h ? atomicAdd(&cursor[b], h) : 0;
    }
    __syncthreads();
    // sweep 2: write records (col/val read coalesced; idx from registers)
    {
        int it = 0;
        for (int i = base + threadIdx.x; i < end; i += L1_THREADS, it++) {
            int col;
            float val;
            if (i < 2 * NNZ1) {
                col = __builtin_nontemporal_load(a1c + i);
                val = __builtin_nontemporal_load(a1v + i);
            } else {
                int j = i - 2 * NNZ1;
                col = __builtin_nontemporal_load(a2c + j);
                val = __builtin_nontemporal_load(a2v + j);
            }
            int idx = idxv[it];
            int pos = atomicAdd(&lh[idx >> 9], 1);
            lvl1[pos] = make_int2(((idx & 511) << 17) | col, __float_as_int(val));
        }
    }
}

// ---------------- level-2 sort within bucket (one block per bucket) ----------------
// Block exclusively owns its destination range [b*CAP, cursor[b]) -> clean
// full-line writes. Emits per-row spans rps/rpe (binned has inter-bucket gaps).
// Final record: 4 B = (fp16(val) << 17) | col  (val in [0,1): sign=0, 15 bits).
__global__ __launch_bounds__(512) void lvl2_sort_kernel(
        const int2* __restrict__ lvl1, const int* __restrict__ cursor,
        int* __restrict__ binned, int* __restrict__ rps, int* __restrict__ rpe) {
    __shared__ int cnt[512];
    __shared__ int sc[512];
    int b = blockIdx.x;
    int t = threadIdx.x;
    int s0 = b * CAP;
    int e0 = cursor[b];   // after lvl1: end of bucket fill
    cnt[t] = 0;
    __syncthreads();
    for (int k = s0 + t; k < e0; k += 512)
        atomicAdd(&cnt[lvl1[k].x >> 17], 1);
    __syncthreads();
    int v = cnt[t];
    sc[t] = v;
    __syncthreads();
    for (int off = 1; off < 512; off <<= 1) {
        int y = (t >= off) ? sc[t - off] : 0;
        __syncthreads();
        sc[t] += y;
        __syncthreads();
    }
    int incl = sc[t];
    int excl = incl - v;
    int idx = (b << 9) + t;
    if (idx < NTOT) {
        rps[idx] = s0 + excl;
        rpe[idx] = s0 + incl;
    }
    cnt[t] = excl;   // repurpose as local cursor
    __syncthreads();
    for (int k = s0 + t; k < e0; k += 512) {
        int2 rec = lvl1[k];
        int rl  = rec.x >> 17;
        int col = rec.x & 0x1FFFF;
        unsigned hv = __half_as_ushort(__float2half(__int_as_float(rec.y)));
        int pos = atomicAdd(&cnt[rl], 1);
        binned[s0 + pos] = (int)((hv << 17) | (unsigned)col);
    }
}

// ---------------- fp16 embedding conversion (unified per-graph layouts) ----------------
// emb1 = [dE; mE] (N1 x 128), emb2 = [pE; mE] (N2 x 128); med rows duplicated.
#define TOT8 ((DIAGNUM + MEDNUM + PRONUM) * (FEATDIM / 8))   // 1,760,000

__device__ __forceinline__ ushort_t f2h(float x) {
    return __half_as_ushort(__float2half(x));
}

__global__ __launch_bounds__(256) void convert_emb_kernel(
        const float* __restrict__ dE, const float* __restrict__ mE,
        const float* __restrict__ pE,
        ushort_t* __restrict__ emb1, ushort_t* __restrict__ emb2) {
    int t8 = blockIdx.x * 256 + threadIdx.x;
    if (t8 >= TOT8) return;
    long flat = (long)t8 * 8;
    const float* src;
    ushort_t* dst;
    ushort_t* dst2 = nullptr;
    if (flat < (long)DIAGNUM * FEATDIM) {
        src = dE + flat;
        dst = emb1 + flat;
    } else if (flat < (long)(DIAGNUM + MEDNUM) * FEATDIM) {
        long o = flat - (long)DIAGNUM * FEATDIM;
        src = mE + o;
        dst  = emb1 + (long)DIAGNUM * FEATDIM + o;
        dst2 = emb2 + (long)PRONUM * FEATDIM + o;
    } else {
        long o = flat - (long)(DIAGNUM + MEDNUM) * FEATDIM;
        src = pE + o;
        dst = emb2 + o;
    }
    float4 a = *reinterpret_cast<const float4*>(src);
    float4 b = *reinterpret_cast<const float4*>(src + 4);
    int4 w;
    w.x = (int)((unsigned)f2h(a.x) | ((unsigned)f2h(a.y) << 16));
    w.y = (int)((unsigned)f2h(a.z) | ((unsigned)f2h(a.w) << 16));
    w.z = (int)((unsigned)f2h(b.x) | ((unsigned)f2h(b.y) << 16));
    w.w = (int)((unsigned)f2h(b.z) | ((unsigned)f2h(b.w) << 16));
    *reinterpret_cast<int4*>(dst) = w;
    if (dst2) *reinterpret_cast<int4*>(dst2) = w;
}

// ---------------- fused GCN row kernel (round-10 form: quarter-wave, 2x unroll) ----------------
// 16 lanes x 16 B (8 fp16) per edge, 8 edges in flight per wave.

__device__ __forceinline__ void fma8(float acc[8], float v, int4 h) {
    union U { int4 i; __half2 h2[4]; } u;
    u.i = h;
#pragma unroll
    for (int j = 0; j < 4; j++) {
        float2 f = __half22float2(u.h2[j]);
        acc[2 * j]     = fmaf(v, f.x, acc[2 * j]);
        acc[2 * j + 1] = fmaf(v, f.y, acc[2 * j + 1]);
    }
}

__device__ __forceinline__ float rec_val(unsigned rec) {
    return __half2float(__ushort_as_half((unsigned short)(rec >> 17)));
}

__device__ __forceinline__ void gather8(int s, int e,
                                        const int* __restrict__ binned,
                                        int q, int sub16,
                                        const ushort_t* __restrict__ emb,
                                        float acc[8]) {
    int k = s + q;
    for (; k + 4 < e; k += 8) {
        unsigned r0 = (unsigned)binned[k];
        unsigned r1 = (unsigned)binned[k + 4];
        const int4* b0 = reinterpret_cast<const int4*>(emb + ((size_t)(r0 & 0x1FFFFu) << 7));
        const int4* b1 = reinterpret_cast<const int4*>(emb + ((size_t)(r1 & 0x1FFFFu) << 7));
        int4 h0 = b0[sub16];
        int4 h1 = b1[sub16];
        fma8(acc, rec_val(r0), h0);
        fma8(acc, rec_val(r1), h1);
    }
    for (; k < e; k += 4) {
        unsigned r0 = (unsigned)binned[k];
        const int4* b0 = reinterpret_cast<const int4*>(emb + ((size_t)(r0 & 0x1FFFFu) << 7));
        int4 h0 = b0[sub16];
        fma8(acc, rec_val(r0), h0);
    }
}

// One 64-lane wave per output row of ONE graph.
// graph==0 (graph2): med rows -> out_m = (1-t)*res (pure write)
// graph==1 (graph1): med rows -> out_m += t*res    (after graph2 launch)
__global__ __launch_bounds__(256) void fused_gcn_kernel(
        const int* __restrict__ rps, const int* __restrict__ rpe,
        const int* __restrict__ binned,
        const ushort_t* __restrict__ emb,   // unified layout for this graph
        const float* __restrict__ inter,
        float* __restrict__ out_d, float* __restrict__ out_p,
        float* __restrict__ out_m, int graph) {
    int gtid = blockIdx.x * blockDim.x + threadIdx.x;
    int w     = gtid >> 6;
    int lane  = gtid & 63;
    int q     = lane >> 4;
    int sub16 = lane & 15;

    int iA, iB, nrows;
    if (graph) { nrows = N1; iA = w;          iB = N1 + w; }
    else       { nrows = N2; iA = 2 * N1 + w; iB = 2 * N1 + N2 + w; }
    if (w >= nrows) return;

    float aA[8] = {0, 0, 0, 0, 0, 0, 0, 0};
    float aB[8] = {0, 0, 0, 0, 0, 0, 0, 0};
    gather8(rps[iA], rpe[iA], binned, q, sub16, emb, aA);
    gather8(rps[iB], rpe[iB], binned, q, sub16, emb, aB);

    // reduce the 4 quarters
#pragma unroll
    for (int j = 0; j < 8; j++) {
        aA[j] += __shfl_xor(aA[j], 16);
        aA[j] += __shfl_xor(aA[j], 32);
        aB[j] += __shfl_xor(aB[j], 16);
        aB[j] += __shfl_xor(aB[j], 32);
    }

    if (lane >= 16) return;

    float r[8];
#pragma unroll
    for (int j = 0; j < 8; j++)
        r[j] = 2.f * (fmaxf(aA[j], 0.f) + fmaxf(aB[j], 0.f));

    float4 lo = make_float4(r[0], r[1], r[2], r[3]);
    float4 hi = make_float4(r[4], r[5], r[6], r[7]);

    if (graph) {
        if (w < DIAGNUM) {
            float4* dst = reinterpret_cast<float4*>(out_d + (size_t)w * FEATDIM);
            dst[sub16 * 2]     = lo;
            dst[sub16 * 2 + 1] = hi;
        } else {
            float t = *inter;
            float4* dst = reinterpret_cast<float4*>(
                out_m + (size_t)(w - DIAGNUM) * FEATDIM);
            float4 o0 = dst[sub16 * 2];
            float4 o1 = dst[sub16 * 2 + 1];
            o0.x = fmaf(t, lo.x, o0.x); o0.y = fmaf(t, lo.y, o0.y);
            o0.z = fmaf(t, lo.z, o0.z); o0.w = fmaf(t, lo.w, o0.w);
            o1.x = fmaf(t, hi.x, o1.x); o1.y = fmaf(t, hi.y, o1.y);
            o1.z = fmaf(t, hi.z, o1.z); o1.w = fmaf(t, hi.w, o1.w);
            dst[sub16 * 2]     = o0;
            dst[sub16 * 2 + 1] = o1;
        }
    } else {
        if (w < PRONUM) {
            float4* dst = reinterpret_cast<float4*>(out_p + (size_t)w * FEATDIM);
            dst[sub16 * 2]     = lo;
            dst[sub16 * 2 + 1] = hi;
        } else {
            float sc = 1.0f - *inter;
            lo.x *= sc; lo.y *= sc; lo.z *= sc; lo.w *= sc;
            hi.x *= sc; hi.y *= sc; hi.z *= sc; hi.w *= sc;
            float4* dst = reinterpret_cast<float4*>(
                out_m + (size_t)(w - PRONUM) * FEATDIM);
            dst[sub16 * 2]     = lo;
            dst[sub16 * 2 + 1] = hi;
        }
    }
}

// ---------------- host orchestration ----------------

extern "C" void kernel_launch(void* const* d_in, const int* in_sizes, int n_in,
                              void* d_out, int out_size, void* d_ws, size_t ws_size,
                              hipStream_t stream) {
    const int*   a1r = (const int*)d_in[0];
    const int*   a1c = (const int*)d_in[1];
    const float* a1v = (const float*)d_in[2];
    const int*   a2r = (const int*)d_in[3];
    const int*   a2c = (const int*)d_in[4];
    const float* a2v = (const float*)d_in[5];
    const float* dE  = (const float*)d_in[6];
    const float* mE  = (const float*)d_in[7];
    const float* pE  = (const float*)d_in[8];
    const float* inter = (const float*)d_in[9];

    float* out   = (float*)d_out;
    float* out_m = out;                               // 20000*128
    float* out_d = out + (size_t)MEDNUM * FEATDIM;    // 50000*128
    float* out_p = out_d + (size_t)DIAGNUM * FEATDIM; // 40000*128

    // ws layout (~55.2 MB). regionB is time-shared: lvl1 int2 records
    // (NBUCK*CAP*8 = 35.37 MB), then fp16 unified embeddings (33.28 MB) —
    // lvl1 dead after lvl2_sort.
    char* ws = (char*)d_ws;
    int* binned = (int*)ws;          ws += (size_t)NBUCK * CAP * 4;     // 17.69 MB
    char* regionB = ws;              ws += (size_t)NBUCK * CAP * 8;     // 35.37 MB
    int2*     lvl1 = (int2*)regionB;
    ushort_t* emb1 = (ushort_t*)regionB;                    // N1*128 fp16
    ushort_t* emb2 = emb1 + (size_t)N1 * FEATDIM;           // N2*128 fp16
    int* rps    = (int*)ws;          ws += (size_t)NTOT * 4;            // 1.04 MB
    int* rpe    = (int*)ws;          ws += (size_t)NTOT * 4;            // 1.04 MB
    int* cursor = (int*)ws;          ws += (size_t)NBUCK * 4;

    const int BLK = 256;

    init_cursor_kernel<<<(NBUCK + BLK - 1) / BLK, BLK, 0, stream>>>(cursor);
    lvl1_scatter_kernel<<<L1_BLOCKS, L1_THREADS, 0, stream>>>(
        a1r, a1c, a1v, a2r, a2c, a2v, cursor, lvl1);
    lvl2_sort_kernel<<<NBUCK, 512, 0, stream>>>(lvl1, cursor, binned, rps, rpe);

    // lvl1 dead now; regionB becomes fp16 embeddings
    convert_emb_kernel<<<(TOT8 + BLK - 1) / BLK, BLK, 0, stream>>>(
        dE, mE, pE, emb1, emb2);

    // graph 2 first (writes out_m pure), then graph 1 (accumulates out_m)
    fused_gcn_kernel<<<(N2 + 3) / 4, BLK, 0, stream>>>(
        rps, rpe, binned, emb2, inter, out_d, out_p, out_m, 0);
    fused_gcn_kernel<<<(N1 + 3) / 4, BLK, 0, stream>>>(
        rps, rpe, binned, emb1, inter, out_d, out_p, out_m, 1);
}